// Round 4
// baseline (4107.069 us; speedup 1.0000x reference)
//
#include <hip/hip_runtime.h>
#include <stdint.h>
#include <math.h>

#define R_  2048
#define E_  256
#define T_  512
#define BT_ 2048
#define SQ_ 225
#define V_  50257
#define NWG_R 64

typedef float f32x4 __attribute__((ext_vector_type(4)));

// ---------------- tiled GEMM 0: Mt[e][s] = sum_r W_in[r][e] * W_ih[s][r] ----------------
__global__ __launch_bounds__(256) void k_gemm_mt(const float* __restrict__ Win,
                                                 const float* __restrict__ Wih,
                                                 float* __restrict__ Mt) {
  __shared__ __align__(16) float As[32][68];
  __shared__ __align__(16) float Bs[32][68];
  const int m0 = blockIdx.x * 64;   // e
  const int n0 = blockIdx.y * 64;   // s
  const int tid = threadIdx.x;
  const int tx = tid & 15, ty = tid >> 4;
  float acc[4][4] = {};
  for (int k0 = 0; k0 < R_; k0 += 32) {
    {
      int mm = tid & 63, kk = tid >> 6; // kk 0..3
#pragma unroll
      for (int u = 0; u < 8; ++u)
        As[kk + u * 4][mm] = Win[(size_t)(k0 + kk + u * 4) * E_ + m0 + mm];
    }
    {
      int kk = tid & 31, nn = tid >> 5; // nn 0..7
#pragma unroll
      for (int u = 0; u < 8; ++u)
        Bs[kk][nn + u * 8] = Wih[(size_t)(n0 + nn + u * 8) * R_ + k0 + kk];
    }
    __syncthreads();
#pragma unroll
    for (int kk = 0; kk < 32; ++kk) {
      float4 a = *(const float4*)&As[kk][ty * 4];
      float4 b = *(const float4*)&Bs[kk][tx * 4];
      acc[0][0] += a.x * b.x; acc[0][1] += a.x * b.y; acc[0][2] += a.x * b.z; acc[0][3] += a.x * b.w;
      acc[1][0] += a.y * b.x; acc[1][1] += a.y * b.y; acc[1][2] += a.y * b.z; acc[1][3] += a.y * b.w;
      acc[2][0] += a.z * b.x; acc[2][1] += a.z * b.y; acc[2][2] += a.z * b.z; acc[2][3] += a.z * b.w;
      acc[3][0] += a.w * b.x; acc[3][1] += a.w * b.y; acc[3][2] += a.w * b.z; acc[3][3] += a.w * b.w;
    }
    __syncthreads();
  }
#pragma unroll
  for (int i = 0; i < 4; ++i) {
    float4 v = make_float4(acc[i][0], acc[i][1], acc[i][2], acc[i][3]);
    *(float4*)&Mt[(size_t)(m0 + ty * 4 + i) * R_ + n0 + tx * 4] = v;
  }
}

// ---------------- tiled GEMM 1: xin[bt][s] = sum_e wte[idx[bt]][e]*Mt[e][s] + b_ih[s] ----
__global__ __launch_bounds__(256) void k_xin(const int* __restrict__ idx,
                                             const float* __restrict__ wte,
                                             const float* __restrict__ Mt,
                                             const float* __restrict__ bih,
                                             float* __restrict__ xin) {
  __shared__ __align__(16) float As[32][68];
  __shared__ __align__(16) float Bs[32][68];
  __shared__ int rowL[64];
  const int m0 = blockIdx.x * 64;   // bt
  const int n0 = blockIdx.y * 64;   // s
  const int tid = threadIdx.x;
  const int tx = tid & 15, ty = tid >> 4;
  if (tid < 64) rowL[tid] = idx[m0 + tid];
  __syncthreads();
  float acc[4][4] = {};
  for (int k0 = 0; k0 < E_; k0 += 32) {
    {
      int kk = tid & 31, mm = tid >> 5; // mm 0..7
#pragma unroll
      for (int u = 0; u < 8; ++u)
        As[kk][mm + u * 8] = wte[(size_t)rowL[mm + u * 8] * E_ + k0 + kk];
    }
    {
      int nn = tid & 63, kk = tid >> 6; // kk 0..3
#pragma unroll
      for (int u = 0; u < 8; ++u)
        Bs[kk + u * 4][nn] = Mt[(size_t)(k0 + kk + u * 4) * R_ + n0 + nn];
    }
    __syncthreads();
#pragma unroll
    for (int kk = 0; kk < 32; ++kk) {
      float4 a = *(const float4*)&As[kk][ty * 4];
      float4 b = *(const float4*)&Bs[kk][tx * 4];
      acc[0][0] += a.x * b.x; acc[0][1] += a.x * b.y; acc[0][2] += a.x * b.z; acc[0][3] += a.x * b.w;
      acc[1][0] += a.y * b.x; acc[1][1] += a.y * b.y; acc[1][2] += a.y * b.z; acc[1][3] += a.y * b.w;
      acc[2][0] += a.z * b.x; acc[2][1] += a.z * b.y; acc[2][2] += a.z * b.z; acc[2][3] += a.z * b.w;
      acc[3][0] += a.w * b.x; acc[3][1] += a.w * b.y; acc[3][2] += a.w * b.z; acc[3][3] += a.w * b.w;
    }
    __syncthreads();
  }
  float4 bv = *(const float4*)&bih[n0 + tx * 4];
#pragma unroll
  for (int i = 0; i < 4; ++i) {
    float4 v = make_float4(acc[i][0] + bv.x, acc[i][1] + bv.y, acc[i][2] + bv.z, acc[i][3] + bv.w);
    *(float4*)&xin[(size_t)(m0 + ty * 4 + i) * R_ + n0 + tx * 4] = v;
  }
}

// ---------------- persistent recurrence: h = tanh(xin_t + W_hh h + b_hh) ----------------
// Sentinel dataflow sync (proven r3), restructured to 64 WGs x 512 threads:
//  - fewer sync participants: 64 publishes, 64 poll targets, half the L3 poll traffic,
//    half the straggler sample -> shorter per-step sync tail
//  - conflict-free LDS remap: each WG block is 128 contiguous floats, lane writes are
//    contiguous 16B within 16-lane groups (linear-equivalent banking; r3's remap was
//    {0,16}-bank scatter -> 1.7e7 conflicts)
//  - st store moved after the h publish (off the visibility-critical chain)
// Protocol (unchanged): hg has 4 slots [4][64][128]; slot t%4 holds h_t, unwritten
// words carry sentinel 0x7F7F7F7F (tanh output can never equal it). Consumers poll
// slot t%4 with sc0/sc1 loads until all words are real -> detection returns the data
// in the same L3 RTT. Each WG re-sentinels its own block of the slot consumed last
// step; that store is vmcnt-drained before this WG's next h-publish, and the 4-slot
// rotation makes the reset visible >= 2 steps before anyone re-polls the slot.
__global__ __launch_bounds__(512, 1) void k_recur(const float* __restrict__ Whh,
                                                  const float* __restrict__ xin,
                                                  const float* __restrict__ bhh_g,
                                                  float* hg,              // [4][64][128]
                                                  float* __restrict__ st) { // [4*512][2048]
  __shared__ __align__(16) float hL[4][R_];
  const int tid = threadIdx.x;
  const int w = tid >> 6;        // wave 0..7 -> rowgroup
  const int c = tid & 63;        // lane -> interleaved r set {k*256 + 4c + j}
  const int row0 = blockIdx.x * 32 + w * 4;

  // W_hh slice in registers: W[i][k*4+j] = Whh[row0+i][k*256 + c*4 + j]
  float W[4][32];
#pragma unroll
  for (int i = 0; i < 4; ++i) {
    const float* src = Whh + (size_t)(row0 + i) * R_;
#pragma unroll
    for (int k = 0; k < 8; ++k) {
      float4 v = *(const float4*)(src + k * 256 + c * 4);
      W[i][k * 4 + 0] = v.x; W[i][k * 4 + 1] = v.y; W[i][k * 4 + 2] = v.z; W[i][k * 4 + 3] = v.w;
    }
  }
  const int li = c >> 2, lb = c & 3;            // lanes 0..15 own output (row0+li, batch lb)
  float bhl = (c < 16) ? bhh_g[row0 + li] : 0.f;

  const unsigned SENT = 0x7F7F7F7Fu;
  f32x4 sent4;
  { union { unsigned u; float f; } cv; cv.u = SENT;
    sent4.x = cv.f; sent4.y = cv.f; sent4.z = cv.f; sent4.w = cv.f; }

  for (int t = 0; t < T_; ++t) {
    // xin is immutable input -> normal cached load, issued early
    float xvl = 0.f;
    if (c < 16) xvl = xin[((size_t)(lb * T_ + t)) * R_ + row0 + li];

    // ---- poll+stage: reload this thread's 4 float4s of slot t&3 until all real ----
    f32x4 tmp[4];
    {
      const f32x4* base = (const f32x4*)(hg + (size_t)(t & 3) * 8192);
      int g = 0;
      for (;;) {
#pragma unroll
        for (int j = 0; j < 4; ++j) {
          const f32x4* ap = base + tid + j * 512;
          asm volatile("global_load_dwordx4 %0, %1, off sc0 sc1"
                       : "=&v"(tmp[j]) : "v"(ap));
        }
        asm volatile("s_waitcnt vmcnt(0)" ::: "memory");
        __builtin_amdgcn_sched_barrier(0);
        bool ok = true;
#pragma unroll
        for (int j = 0; j < 4; ++j) {
          ok = ok && (__float_as_uint(tmp[j].x) != SENT) && (__float_as_uint(tmp[j].y) != SENT)
                  && (__float_as_uint(tmp[j].z) != SENT) && (__float_as_uint(tmp[j].w) != SENT);
        }
        if (ok) break;
        if (++g > 2048) break;            // fail-safe: terminate (wrong) rather than hang
        __builtin_amdgcn_s_sleep(2);      // backoff: avoid coherent-read storm on L3
      }
    }

    // ---- re-sentinel own 128-float block of the slot consumed LAST step ----
    // Safe: reaching here means all WGs published h_t, i.e. everyone finished reading
    // slot (t-1)&3. Drained by the vmcnt(0) below before this WG's next publish.
    if (tid < 32) {
      float* rb = hg + (size_t)((t + 3) & 3) * 8192 + blockIdx.x * 128 + tid * 4;
      asm volatile("global_store_dwordx4 %0, %1, off sc0 sc1"
                   :: "v"(rb), "v"(sent4) : "memory");
    }

    // ---- LDS stage: slot[wg][lb*32+rl] -> hL[lb][wg*32+rl] (contiguous per lane) ----
#pragma unroll
    for (int j = 0; j < 4; ++j) {
      int q = tid + j * 512;              // float4 index into slot (0..2047)
      int wg = q >> 5;                    // owning WG block (128 floats = 32 float4)
      int b  = (q >> 3) & 3;              // batch within block
      int rl = (q & 7) << 2;              // float offset within 32-row span
      *(f32x4*)&hL[b][wg * 32 + rl] = tmp[j];
    }
    __syncthreads();

    float acc[4][4] = {};
#pragma unroll
    for (int k = 0; k < 8; ++k) {
      float4 h4[4];
#pragma unroll
      for (int b = 0; b < 4; ++b) h4[b] = *(const float4*)&hL[b][k * 256 + c * 4];
#pragma unroll
      for (int i = 0; i < 4; ++i) {
#pragma unroll
        for (int b = 0; b < 4; ++b) {
          acc[i][b] += W[i][k * 4 + 0] * h4[b].x + W[i][k * 4 + 1] * h4[b].y
                     + W[i][k * 4 + 2] * h4[b].z + W[i][k * 4 + 3] * h4[b].w;
        }
      }
    }
    // butterfly reduce across 64 lanes for each of the 16 accumulators
#pragma unroll
    for (int i = 0; i < 4; ++i)
#pragma unroll
      for (int b = 0; b < 4; ++b) {
        float v = acc[i][b];
        v += __shfl_xor(v, 32); v += __shfl_xor(v, 16); v += __shfl_xor(v, 8);
        v += __shfl_xor(v, 4);  v += __shfl_xor(v, 2);  v += __shfl_xor(v, 1);
        acc[i][b] = v;
      }
    if (c < 16) {
      float val = acc[0][0];
#pragma unroll
      for (int i = 0; i < 4; ++i)
#pragma unroll
        for (int b = 0; b < 4; ++b) {
          int k = i * 4 + b;
          if (k > 0) val = (c == k) ? acc[i][b] : val;
        }
      float hn = tanhf(xvl + val + bhl);
      // ensure the re-sentinel store is at L3 before the new h is observable
      asm volatile("s_waitcnt vmcnt(0)" ::: "memory");
      // publish h_{t+1} into slot (t+1)&3, own block, write-through to coherence point
      __hip_atomic_store(&hg[(size_t)((t + 1) & 3) * 8192 + blockIdx.x * 128
                             + lb * 32 + w * 4 + li],
                         hn, __ATOMIC_RELAXED, __HIP_MEMORY_SCOPE_AGENT);
      st[((size_t)(lb * T_ + t)) * R_ + row0 + li] = hn;   // off critical path, later dispatch
    }
    // NO end-of-step barrier: a wave can only pass the next poll after ALL waves of
    // ALL WGs (incl. its own) published h_{t+1}, which implies their hL reads are done.
  }
}

// ---------------- tiled GEMM 2: logits heads ----------------
__global__ __launch_bounds__(256) void k_logits(const float* __restrict__ stt,
                                                const float* __restrict__ Wh1,
                                                const float* __restrict__ Wh2,
                                                float* __restrict__ lg1,
                                                float* __restrict__ lg2) {
  __shared__ __align__(16) float As[32][68];
  __shared__ __align__(16) float Bs[32][68];
  const int m0 = blockIdx.x * 64;   // bt
  const int n0 = blockIdx.y * 64;   // v (0..511, valid < 450)
  const int tid = threadIdx.x;
  const int tx = tid & 15, ty = tid >> 4;
  float acc[4][4] = {};
  for (int k0 = 0; k0 < R_; k0 += 32) {
    {
      int kk = tid & 31, mm = tid >> 5;
#pragma unroll
      for (int u = 0; u < 8; ++u)
        As[kk][mm + u * 8] = stt[(size_t)(m0 + mm + u * 8) * R_ + k0 + kk];
    }
    {
      int kk = tid & 31, nn = tid >> 5;
#pragma unroll
      for (int u = 0; u < 8; ++u) {
        int n = n0 + nn + u * 8;
        float v = 0.f;
        if (n < SQ_)            v = Wh1[(size_t)n * R_ + k0 + kk];
        else if (n < 2 * SQ_)   v = Wh2[(size_t)(n - SQ_) * R_ + k0 + kk];
        Bs[kk][nn + u * 8] = v;
      }
    }
    __syncthreads();
#pragma unroll
    for (int kk = 0; kk < 32; ++kk) {
      float4 a = *(const float4*)&As[kk][ty * 4];
      float4 b = *(const float4*)&Bs[kk][tx * 4];
      acc[0][0] += a.x * b.x; acc[0][1] += a.x * b.y; acc[0][2] += a.x * b.z; acc[0][3] += a.x * b.w;
      acc[1][0] += a.y * b.x; acc[1][1] += a.y * b.y; acc[1][2] += a.y * b.z; acc[1][3] += a.y * b.w;
      acc[2][0] += a.z * b.x; acc[2][1] += a.z * b.y; acc[2][2] += a.z * b.z; acc[2][3] += a.z * b.w;
      acc[3][0] += a.w * b.x; acc[3][1] += a.w * b.y; acc[3][2] += a.w * b.z; acc[3][3] += a.w * b.w;
    }
    __syncthreads();
  }
#pragma unroll
  for (int i = 0; i < 4; ++i)
#pragma unroll
    for (int j = 0; j < 4; ++j) {
      int n = n0 + tx * 4 + j;
      int m = m0 + ty * 4 + i;
      if (n < SQ_)          lg1[(size_t)m * 256 + n] = acc[i][j];
      else if (n < 2 * SQ_) lg2[(size_t)m * 256 + (n - SQ_)] = acc[i][j];
    }
}

// ---------------- log_softmax (225) + masked NLL accumulation ----------------
__global__ __launch_bounds__(256) void k_lsm(float* lg1, float* lg2,
                                             const int* __restrict__ tgt, float* ctrl) {
  const int bt = blockIdx.x;
  const int head = blockIdx.y;
  float* lg = (head ? lg2 : lg1) + (size_t)bt * 256;
  const int tid = threadIdx.x;
  __shared__ float red[8];
  float x = (tid < SQ_) ? lg[tid] : -1e30f;
  float m = x;
#pragma unroll
  for (int o = 32; o >= 1; o >>= 1) m = fmaxf(m, __shfl_down(m, o));
  if ((tid & 63) == 0) red[tid >> 6] = m;
  __syncthreads();
  if (tid == 0) red[4] = fmaxf(fmaxf(red[0], red[1]), fmaxf(red[2], red[3]));
  __syncthreads();
  float mx = red[4];
  float e = (tid < SQ_) ? __expf(x - mx) : 0.f;
  float s = e;
#pragma unroll
  for (int o = 32; o >= 1; o >>= 1) s += __shfl_down(s, o);
  if ((tid & 63) == 0) red[tid >> 6] = s;
  __syncthreads();
  if (tid == 0) red[5] = logf(red[0] + red[1] + red[2] + red[3]);
  __syncthreads();
  float lp = x - mx - red[5];
  if (tid < SQ_) lg[tid] = lp;
  int t = tgt[bt];
  if (t != -1) {
    int trow = (int)(((uint64_t)(unsigned)t * 19088744ULL) >> 32);
    int tcol = t - trow * 225;
    int want = head ? tcol : trow;
    if (tid == want) atomicAdd(&ctrl[1], -lp);
    if (head == 0 && tid == 0) atomicAdd((int*)ctrl + 2, 1);
  }
}

// ---------------- final 412MB logits write: lp1[row] + lp2[col] ----------------
__global__ __launch_bounds__(256) void k_write(const float* __restrict__ lg1,
                                               const float* __restrict__ lg2,
                                               float* __restrict__ out) {
  __shared__ float l1[SQ_], l2[SQ_];
  const int bt = blockIdx.x;
  const int tid = threadIdx.x;
  if (tid < SQ_) {
    l1[tid] = lg1[(size_t)bt * 256 + tid];
    l2[tid] = lg2[(size_t)bt * 256 + tid];
  }
  __syncthreads();
  const int vbase = blockIdx.y * 4096;
  float* o = out + (size_t)bt * V_;
#pragma unroll
  for (int i = 0; i < 16; ++i) {
    int v = vbase + i * 256 + tid;
    if (v < V_) {
      int row = (int)(((uint64_t)(unsigned)v * 19088744ULL) >> 32);
      int col = v - row * 225;
      o[v] = l1[row] + l2[col];
    }
  }
}

// ---------------- tail: loss scalar + h_n copy (remap WG-blocked h) ----------------
__global__ __launch_bounds__(256) void k_tail(const float* __restrict__ hg,
                                              const float* __restrict__ ctrl,
                                              float* __restrict__ out) {
  int i = blockIdx.x * 256 + threadIdx.x;
  if (i < 8192) {
    // h_512 lives in slot 0 (512 % 4 == 0), layout [wg(64)][lb*32 + rl]
    int lb = i >> 11, r = i & 2047;
    int wg = r >> 5, rl = r & 31;
    out[(size_t)BT_ * V_ + 1 + i] = hg[wg * 128 + lb * 32 + rl];
  } else if (i == 8192) {
    int cnt = ((const int*)ctrl)[2];
    if (cnt < 1) cnt = 1;
    out[(size_t)BT_ * V_] = ctrl[1] / (float)cnt;
  }
}

extern "C" void kernel_launch(void* const* d_in, const int* in_sizes, int n_in,
                              void* d_out, int out_size, void* d_ws, size_t ws_size,
                              hipStream_t stream) {
  (void)in_sizes; (void)n_in; (void)out_size; (void)ws_size;
  const int*   idx = (const int*)d_in[0];
  const int*   tgt = (const int*)d_in[1];
  const float* wte = (const float*)d_in[2];
  const float* Win = (const float*)d_in[3];
  const float* Wih = (const float*)d_in[4];
  const float* bih = (const float*)d_in[5];
  const float* Whh = (const float*)d_in[6];
  const float* bhh = (const float*)d_in[7];
  const float* Wh1 = (const float*)d_in[8];
  const float* Wh2 = (const float*)d_in[9];

  float* ws   = (float*)d_ws;
  float* ctrl = ws;                        // [1] loss acc, [2] cnt
  float* hg   = ws + 64;                   // 4 slots x 8192 (WG-blocked, 64 blocks)
  float* Mt   = hg + 4 * 8192;             // 256*2048
  float* xin  = Mt + (size_t)E_ * R_;      // 2048*2048
  float* st   = xin + (size_t)BT_ * R_;    // 2048*2048
  float* lg1  = xin;                       // overlay: xin dead after k_recur
  float* lg2  = xin + (size_t)BT_ * 256;
  float* out  = (float*)d_out;

  // ctrl + slot 0 (= h_0 zeros) cleared; slots 1-3 filled with sentinel bytes 0x7F
  hipMemsetAsync(ws, 0, (64 + 8192) * sizeof(float), stream);
  hipMemsetAsync(hg + 8192, 0x7F, 3 * 8192 * sizeof(float), stream);
  k_gemm_mt<<<dim3(E_ / 64, R_ / 64), 256, 0, stream>>>(Win, Wih, Mt);
  k_xin<<<dim3(BT_ / 64, R_ / 64), 256, 0, stream>>>(idx, wte, Mt, bih, xin);
  k_recur<<<dim3(NWG_R), 512, 0, stream>>>(Whh, xin, bhh, hg, st);
  k_logits<<<dim3(BT_ / 64, 8), 256, 0, stream>>>(st, Wh1, Wh2, lg1, lg2);
  k_lsm<<<dim3(BT_, 2), 256, 0, stream>>>(lg1, lg2, tgt, ctrl);
  k_write<<<dim3(BT_, 13), 256, 0, stream>>>(lg1, lg2, out);
  k_tail<<<dim3(33), 256, 0, stream>>>(hg, ctrl, out);
}

// Round 5
// 3447.618 us; speedup vs baseline: 1.1913x; 1.1913x over previous
//
#include <hip/hip_runtime.h>
#include <stdint.h>
#include <math.h>

#define R_  2048
#define E_  256
#define T_  512
#define BT_ 2048
#define SQ_ 225
#define V_  50257
#define NWG_R 128

typedef float f32x4 __attribute__((ext_vector_type(4)));

// ---------------- tiled GEMM 0: Mt[e][s] = sum_r W_in[r][e] * W_ih[s][r] ----------------
__global__ __launch_bounds__(256) void k_gemm_mt(const float* __restrict__ Win,
                                                 const float* __restrict__ Wih,
                                                 float* __restrict__ Mt) {
  __shared__ __align__(16) float As[32][68];
  __shared__ __align__(16) float Bs[32][68];
  const int m0 = blockIdx.x * 64;   // e
  const int n0 = blockIdx.y * 64;   // s
  const int tid = threadIdx.x;
  const int tx = tid & 15, ty = tid >> 4;
  float acc[4][4] = {};
  for (int k0 = 0; k0 < R_; k0 += 32) {
    {
      int mm = tid & 63, kk = tid >> 6; // kk 0..3
#pragma unroll
      for (int u = 0; u < 8; ++u)
        As[kk + u * 4][mm] = Win[(size_t)(k0 + kk + u * 4) * E_ + m0 + mm];
    }
    {
      int kk = tid & 31, nn = tid >> 5; // nn 0..7
#pragma unroll
      for (int u = 0; u < 8; ++u)
        Bs[kk][nn + u * 8] = Wih[(size_t)(n0 + nn + u * 8) * R_ + k0 + kk];
    }
    __syncthreads();
#pragma unroll
    for (int kk = 0; kk < 32; ++kk) {
      float4 a = *(const float4*)&As[kk][ty * 4];
      float4 b = *(const float4*)&Bs[kk][tx * 4];
      acc[0][0] += a.x * b.x; acc[0][1] += a.x * b.y; acc[0][2] += a.x * b.z; acc[0][3] += a.x * b.w;
      acc[1][0] += a.y * b.x; acc[1][1] += a.y * b.y; acc[1][2] += a.y * b.z; acc[1][3] += a.y * b.w;
      acc[2][0] += a.z * b.x; acc[2][1] += a.z * b.y; acc[2][2] += a.z * b.z; acc[2][3] += a.z * b.w;
      acc[3][0] += a.w * b.x; acc[3][1] += a.w * b.y; acc[3][2] += a.w * b.z; acc[3][3] += a.w * b.w;
    }
    __syncthreads();
  }
#pragma unroll
  for (int i = 0; i < 4; ++i) {
    float4 v = make_float4(acc[i][0], acc[i][1], acc[i][2], acc[i][3]);
    *(float4*)&Mt[(size_t)(m0 + ty * 4 + i) * R_ + n0 + tx * 4] = v;
  }
}

// ------ tiled GEMM 1: xinT[s][bt] = sum_e wte[idx[bt]][e]*Mt[e][s] + b_ih[s] (transposed) --
__global__ __launch_bounds__(256) void k_xin(const int* __restrict__ idx,
                                             const float* __restrict__ wte,
                                             const float* __restrict__ Mt,
                                             const float* __restrict__ bih,
                                             float* __restrict__ xinT) {
  __shared__ __align__(16) float As[32][68];
  __shared__ __align__(16) float Bs[32][68];
  __shared__ __align__(16) float Ts[64][68];
  __shared__ int rowL[64];
  const int m0 = blockIdx.x * 64;   // bt
  const int n0 = blockIdx.y * 64;   // s
  const int tid = threadIdx.x;
  const int tx = tid & 15, ty = tid >> 4;
  if (tid < 64) rowL[tid] = idx[m0 + tid];
  __syncthreads();
  float acc[4][4] = {};
  for (int k0 = 0; k0 < E_; k0 += 32) {
    {
      int kk = tid & 31, mm = tid >> 5; // mm 0..7
#pragma unroll
      for (int u = 0; u < 8; ++u)
        As[kk][mm + u * 8] = wte[(size_t)rowL[mm + u * 8] * E_ + k0 + kk];
    }
    {
      int nn = tid & 63, kk = tid >> 6; // kk 0..3
#pragma unroll
      for (int u = 0; u < 8; ++u)
        Bs[kk + u * 4][nn] = Mt[(size_t)(k0 + kk + u * 4) * R_ + n0 + nn];
    }
    __syncthreads();
#pragma unroll
    for (int kk = 0; kk < 32; ++kk) {
      float4 a = *(const float4*)&As[kk][ty * 4];
      float4 b = *(const float4*)&Bs[kk][tx * 4];
      acc[0][0] += a.x * b.x; acc[0][1] += a.x * b.y; acc[0][2] += a.x * b.z; acc[0][3] += a.x * b.w;
      acc[1][0] += a.y * b.x; acc[1][1] += a.y * b.y; acc[1][2] += a.y * b.z; acc[1][3] += a.y * b.w;
      acc[2][0] += a.z * b.x; acc[2][1] += a.z * b.y; acc[2][2] += a.z * b.z; acc[2][3] += a.z * b.w;
      acc[3][0] += a.w * b.x; acc[3][1] += a.w * b.y; acc[3][2] += a.w * b.z; acc[3][3] += a.w * b.w;
    }
    __syncthreads();
  }
  float4 bv = *(const float4*)&bih[n0 + tx * 4];
  // transpose tile in LDS: Ts[n_local][m_local]
#pragma unroll
  for (int i = 0; i < 4; ++i) {
    Ts[tx * 4 + 0][ty * 4 + i] = acc[i][0] + bv.x;
    Ts[tx * 4 + 1][ty * 4 + i] = acc[i][1] + bv.y;
    Ts[tx * 4 + 2][ty * 4 + i] = acc[i][2] + bv.z;
    Ts[tx * 4 + 3][ty * 4 + i] = acc[i][3] + bv.w;
  }
  __syncthreads();
  {
    int nn = tid >> 2, qq = tid & 3;   // row n_local, quarter
#pragma unroll
    for (int u = 0; u < 4; ++u) {
      float4 v = *(const float4*)&Ts[nn][(qq + u * 4) * 4];
      *(float4*)&xinT[(size_t)(n0 + nn) * BT_ + m0 + (qq + u * 4) * 4] = v;
    }
  }
}

// ---------------- persistent recurrence: h = tanh(xin_t + W_hh h + b_hh) ----------------
// R1 flag protocol (proven) with a shortened chain:
//  - every lane polls flags[c] and flags[c+64] -> each wave independently observes all
//    128 publishes -> NO barrier between poll and stage (stage issues per-wave on detect)
//  - NO trailing barrier / threadfence (flag-after-barrier carries the ordering;
//    stage loads are sc0/sc1 L2-bypass)
//  - st values buffered in double-buffered LDS (stS[2][8][.]) and bulk-flushed once per
//    8 steps as coalesced float4 into transposed stT[r][b*T+t] -> scattered per-step
//    global stores (and their acks at every barrier's vmcnt(0)) are gone. Reuse of a
//    stS buffer is 16 steps away and flag-gated -> provably race-free.
//  - xinT[r][b*T+t]: per-step xin read walks contiguous t (one 128B line / 32 steps)
__global__ __launch_bounds__(256, 1) void k_recur(const float* __restrict__ Whh,
                                                  const float* __restrict__ xinT,
                                                  const float* __restrict__ bhh_g,
                                                  float* hg,               // [2][4][2048]
                                                  float* __restrict__ stT, // [2048][2048] r-major
                                                  unsigned* flags) {       // [128] stride 16 u32
  __shared__ __align__(16) float hL[4][R_];
  __shared__ float stS[2][8][72];
  const int tid = threadIdx.x;
  const int w = tid >> 6;        // wave -> rowgroup
  const int c = tid & 63;        // lane -> interleaved r set {k*256 + 4c + j}
  const int row0 = blockIdx.x * 16 + w * 4;

  // W_hh slice in registers: W[i][k*4+j] = Whh[row0+i][k*256 + c*4 + j]
  float W[4][32];
#pragma unroll
  for (int i = 0; i < 4; ++i) {
    const float* src = Whh + (size_t)(row0 + i) * R_;
#pragma unroll
    for (int k = 0; k < 8; ++k) {
      float4 v = *(const float4*)(src + k * 256 + c * 4);
      W[i][k * 4 + 0] = v.x; W[i][k * 4 + 1] = v.y; W[i][k * 4 + 2] = v.z; W[i][k * 4 + 3] = v.w;
    }
  }
  const int li = c >> 2, lb = c & 3;            // lanes 0..15 own output (row0+li, batch lb)
  float bhl = (c < 16) ? bhh_g[row0 + li] : 0.f;
  // flush roles (tid < 128): row fr, batch flb, half fth
  const int fr = tid >> 3, flb = (tid >> 1) & 3, fth = tid & 1;

  for (int t = 0; t < T_; ++t) {
    const int p = t & 1;
    // xin: immutable, transposed layout -> contiguous t, L1/L2 line reuse
    float xvl = 0.f;
    if (c < 16) xvl = xinT[(size_t)(row0 + li) * BT_ + lb * T_ + t];

    // dataflow gate: EVERY lane polls two flags -> whole wave sees all 128 publishes
    if (t) {
      const unsigned* f0 = flags + (size_t)c * 16;
      const unsigned* f1 = flags + (size_t)(c + 64) * 16;
      long g = 0;
      while (__hip_atomic_load(f0, __ATOMIC_RELAXED, __HIP_MEMORY_SCOPE_AGENT) < (unsigned)t ||
             __hip_atomic_load(f1, __ATOMIC_RELAXED, __HIP_MEMORY_SCOPE_AGENT) < (unsigned)t) {
        __builtin_amdgcn_s_sleep(1);
        if (++g > (1L << 24)) break;   // safety valve
      }
    }

    // stage h_t into LDS via coherent 16B loads; issues immediately after this wave's detect
    {
      const f32x4* hsrc = (const f32x4*)(hg + (size_t)p * 8192);
      f32x4 tmp[8];
#pragma unroll
      for (int j = 0; j < 8; ++j) {
        const f32x4* ap = hsrc + tid + j * 256;
        asm volatile("global_load_dwordx4 %0, %1, off sc0 sc1" : "=&v"(tmp[j]) : "v"(ap));
      }
      asm volatile("s_waitcnt vmcnt(0)" ::: "memory");
      __builtin_amdgcn_sched_barrier(0);
      f32x4* hLv = (f32x4*)hL;
#pragma unroll
      for (int j = 0; j < 8; ++j) hLv[tid + j * 256] = tmp[j];
    }
    __syncthreads();

    float acc[4][4] = {};
#pragma unroll
    for (int k = 0; k < 8; ++k) {
      float4 h4[4];
#pragma unroll
      for (int b = 0; b < 4; ++b) h4[b] = *(const float4*)&hL[b][k * 256 + c * 4];
#pragma unroll
      for (int i = 0; i < 4; ++i) {
#pragma unroll
        for (int b = 0; b < 4; ++b) {
          acc[i][b] += W[i][k * 4 + 0] * h4[b].x + W[i][k * 4 + 1] * h4[b].y
                     + W[i][k * 4 + 2] * h4[b].z + W[i][k * 4 + 3] * h4[b].w;
        }
      }
    }
    // butterfly reduce across 64 lanes for each of the 16 accumulators
#pragma unroll
    for (int i = 0; i < 4; ++i)
#pragma unroll
      for (int b = 0; b < 4; ++b) {
        float v = acc[i][b];
        v += __shfl_xor(v, 32); v += __shfl_xor(v, 16); v += __shfl_xor(v, 8);
        v += __shfl_xor(v, 4);  v += __shfl_xor(v, 2);  v += __shfl_xor(v, 1);
        acc[i][b] = v;
      }
    if (c < 16) {
      float val = acc[0][0];
#pragma unroll
      for (int i = 0; i < 4; ++i)
#pragma unroll
        for (int b = 0; b < 4; ++b) {
          int k = i * 4 + b;
          if (k > 0) val = (c == k) ? acc[i][b] : val;
        }
      float hn = tanhf(xvl + val + bhl);
      // publish h_{t+1}: write-through to coherence point (L3)
      __hip_atomic_store(&hg[(size_t)(1 - p) * 8192 + lb * R_ + row0 + li], hn,
                         __ATOMIC_RELAXED, __HIP_MEMORY_SCOPE_AGENT);
      stS[(t >> 3) & 1][t & 7][lb * 16 + w * 4 + li] = hn;   // LDS, no vmem ack
    }
    __syncthreads();   // each wave drains its own publish (vmcnt(0) before s_barrier)
    if (tid == 0) {
      __hip_atomic_store(flags + (size_t)blockIdx.x * 16, (unsigned)(t + 1),
                         __ATOMIC_RELAXED, __HIP_MEMORY_SCOPE_AGENT);
    }
    // bulk st flush once per 8 steps (coalesced, off the critical sync chain)
    if ((t & 7) == 7 && tid < 128) {
      const int buf = (t >> 3) & 1, t0 = t - 7;
      f32x4 v;
      v.x = stS[buf][fth * 4 + 0][flb * 16 + fr];
      v.y = stS[buf][fth * 4 + 1][flb * 16 + fr];
      v.z = stS[buf][fth * 4 + 2][flb * 16 + fr];
      v.w = stS[buf][fth * 4 + 3][flb * 16 + fr];
      *(f32x4*)&stT[(size_t)(blockIdx.x * 16 + fr) * BT_ + flb * T_ + t0 + fth * 4] = v;
    }
    // NO trailing barrier: flag-after-barrier + 2-slot rotation carry the ordering (R1 logic)
  }
}

// ---------------- tiled GEMM 2: logits heads (A = stT, r-major) ----------------
__global__ __launch_bounds__(256) void k_logits(const float* __restrict__ stT,
                                                const float* __restrict__ Wh1,
                                                const float* __restrict__ Wh2,
                                                float* __restrict__ lg1,
                                                float* __restrict__ lg2) {
  __shared__ __align__(16) float As[32][68];
  __shared__ __align__(16) float Bs[32][68];
  const int m0 = blockIdx.x * 64;   // bt
  const int n0 = blockIdx.y * 64;   // v (0..511, valid < 450)
  const int tid = threadIdx.x;
  const int tx = tid & 15, ty = tid >> 4;
  float acc[4][4] = {};
  for (int k0 = 0; k0 < R_; k0 += 32) {
    {
      int mm = tid & 63, kk = tid >> 6; // kk 0..3
#pragma unroll
      for (int u = 0; u < 8; ++u)
        As[kk + u * 4][mm] = stT[(size_t)(k0 + kk + u * 4) * BT_ + m0 + mm];
    }
    {
      int kk = tid & 31, nn = tid >> 5;
#pragma unroll
      for (int u = 0; u < 8; ++u) {
        int n = n0 + nn + u * 8;
        float v = 0.f;
        if (n < SQ_)            v = Wh1[(size_t)n * R_ + k0 + kk];
        else if (n < 2 * SQ_)   v = Wh2[(size_t)(n - SQ_) * R_ + k0 + kk];
        Bs[kk][nn + u * 8] = v;
      }
    }
    __syncthreads();
#pragma unroll
    for (int kk = 0; kk < 32; ++kk) {
      float4 a = *(const float4*)&As[kk][ty * 4];
      float4 b = *(const float4*)&Bs[kk][tx * 4];
      acc[0][0] += a.x * b.x; acc[0][1] += a.x * b.y; acc[0][2] += a.x * b.z; acc[0][3] += a.x * b.w;
      acc[1][0] += a.y * b.x; acc[1][1] += a.y * b.y; acc[1][2] += a.y * b.z; acc[1][3] += a.y * b.w;
      acc[2][0] += a.z * b.x; acc[2][1] += a.z * b.y; acc[2][2] += a.z * b.z; acc[2][3] += a.z * b.w;
      acc[3][0] += a.w * b.x; acc[3][1] += a.w * b.y; acc[3][2] += a.w * b.z; acc[3][3] += a.w * b.w;
    }
    __syncthreads();
  }
#pragma unroll
  for (int i = 0; i < 4; ++i)
#pragma unroll
    for (int j = 0; j < 4; ++j) {
      int n = n0 + tx * 4 + j;
      int m = m0 + ty * 4 + i;
      if (n < SQ_)          lg1[(size_t)m * 256 + n] = acc[i][j];
      else if (n < 2 * SQ_) lg2[(size_t)m * 256 + (n - SQ_)] = acc[i][j];
    }
}

// ---------------- log_softmax (225) + masked NLL accumulation ----------------
__global__ __launch_bounds__(256) void k_lsm(float* lg1, float* lg2,
                                             const int* __restrict__ tgt, float* ctrl) {
  const int bt = blockIdx.x;
  const int head = blockIdx.y;
  float* lg = (head ? lg2 : lg1) + (size_t)bt * 256;
  const int tid = threadIdx.x;
  __shared__ float red[8];
  float x = (tid < SQ_) ? lg[tid] : -1e30f;
  float m = x;
#pragma unroll
  for (int o = 32; o >= 1; o >>= 1) m = fmaxf(m, __shfl_down(m, o));
  if ((tid & 63) == 0) red[tid >> 6] = m;
  __syncthreads();
  if (tid == 0) red[4] = fmaxf(fmaxf(red[0], red[1]), fmaxf(red[2], red[3]));
  __syncthreads();
  float mx = red[4];
  float e = (tid < SQ_) ? __expf(x - mx) : 0.f;
  float s = e;
#pragma unroll
  for (int o = 32; o >= 1; o >>= 1) s += __shfl_down(s, o);
  if ((tid & 63) == 0) red[tid >> 6] = s;
  __syncthreads();
  if (tid == 0) red[5] = logf(red[0] + red[1] + red[2] + red[3]);
  __syncthreads();
  float lp = x - mx - red[5];
  if (tid < SQ_) lg[tid] = lp;
  int t = tgt[bt];
  if (t != -1) {
    int trow = (int)(((uint64_t)(unsigned)t * 19088744ULL) >> 32);
    int tcol = t - trow * 225;
    int want = head ? tcol : trow;
    if (tid == want) atomicAdd(&ctrl[1], -lp);
    if (head == 0 && tid == 0) atomicAdd((int*)ctrl + 2, 1);
  }
}

// ---------------- final 412MB logits write: lp1[row] + lp2[col] ----------------
__global__ __launch_bounds__(256) void k_write(const float* __restrict__ lg1,
                                               const float* __restrict__ lg2,
                                               float* __restrict__ out) {
  __shared__ float l1[SQ_], l2[SQ_];
  const int bt = blockIdx.x;
  const int tid = threadIdx.x;
  if (tid < SQ_) {
    l1[tid] = lg1[(size_t)bt * 256 + tid];
    l2[tid] = lg2[(size_t)bt * 256 + tid];
  }
  __syncthreads();
  const int vbase = blockIdx.y * 4096;
  float* o = out + (size_t)bt * V_;
#pragma unroll
  for (int i = 0; i < 16; ++i) {
    int v = vbase + i * 256 + tid;
    if (v < V_) {
      int row = (int)(((uint64_t)(unsigned)v * 19088744ULL) >> 32);
      int col = v - row * 225;
      o[v] = l1[row] + l2[col];
    }
  }
}

// ---------------- tail: loss scalar + h_n copy ----------------
__global__ __launch_bounds__(256) void k_tail(const float* __restrict__ hg,
                                              const float* __restrict__ ctrl,
                                              float* __restrict__ out) {
  int i = blockIdx.x * 256 + threadIdx.x;
  if (i < 8192) {
    out[(size_t)BT_ * V_ + 1 + i] = hg[i];   // final h is in buffer 0 (512 even steps)
  } else if (i == 8192) {
    int cnt = ((const int*)ctrl)[2];
    if (cnt < 1) cnt = 1;
    out[(size_t)BT_ * V_] = ctrl[1] / (float)cnt;
  }
}

extern "C" void kernel_launch(void* const* d_in, const int* in_sizes, int n_in,
                              void* d_out, int out_size, void* d_ws, size_t ws_size,
                              hipStream_t stream) {
  (void)in_sizes; (void)n_in; (void)out_size; (void)ws_size;
  const int*   idx = (const int*)d_in[0];
  const int*   tgt = (const int*)d_in[1];
  const float* wte = (const float*)d_in[2];
  const float* Win = (const float*)d_in[3];
  const float* Wih = (const float*)d_in[4];
  const float* bih = (const float*)d_in[5];
  const float* Whh = (const float*)d_in[6];
  const float* bhh = (const float*)d_in[7];
  const float* Wh1 = (const float*)d_in[8];
  const float* Wh2 = (const float*)d_in[9];

  float* ws    = (float*)d_ws;
  float* ctrl  = ws;                        // [1] loss acc, [2] cnt
  unsigned* fl = (unsigned*)(ws + 64);      // 128 flags, stride 16 u32 (64B lines)
  float* hg    = ws + 64 + 2048;            // 2*4*2048
  float* Mt    = hg + 16384;                // 256*2048
  float* xinT  = Mt + (size_t)E_ * R_;      // 2048*2048  [s][bt]
  float* stT   = xinT + (size_t)BT_ * R_;   // 2048*2048  [r][b*T+t]
  float* lg1   = xinT;                      // overlay: xinT dead after k_recur
  float* lg2   = xinT + (size_t)BT_ * 256;
  float* out   = (float*)d_out;

  hipMemsetAsync(d_ws, 0, (64 + 2048 + 16384) * sizeof(float), stream);
  k_gemm_mt<<<dim3(E_ / 64, R_ / 64), 256, 0, stream>>>(Win, Wih, Mt);
  k_xin<<<dim3(BT_ / 64, R_ / 64), 256, 0, stream>>>(idx, wte, Mt, bih, xinT);
  k_recur<<<dim3(NWG_R), 256, 0, stream>>>(Whh, xinT, bhh, hg, stT, fl);
  k_logits<<<dim3(BT_ / 64, 8), 256, 0, stream>>>(stT, Wh1, Wh2, lg1, lg2);
  k_lsm<<<dim3(BT_, 2), 256, 0, stream>>>(lg1, lg2, tgt, ctrl);
  k_write<<<dim3(BT_, 13), 256, 0, stream>>>(lg1, lg2, out);
  k_tail<<<dim3(33), 256, 0, stream>>>(hg, ctrl, out);
}